// Round 7
// baseline (2470.736 us; speedup 1.0000x reference)
//
#include <hip/hip_runtime.h>

#define N_NODES 100000
#define IN_DIM 256
#define OUT_DIM 128
#define N_EDGES 3200000

#define NB 3125            // 100000 / 32 EXACT buckets of 32 dst nodes (no tail)
#define CAP 1272           // bucket capacity; mean 1024, sigma 32 -> +7.75 sigma
#define PTILE 6400         // edges per partition block (R4-proven)
#define PBLK 500           // 500 * 6400 = 3.2M exactly
#define GBLK 782           // ceil(100000 / 128) gemm blocks (8 waves x 16 rows)

typedef __attribute__((ext_vector_type(8))) short short8;   // 8 bf16 (4 VGPRs)
typedef __attribute__((ext_vector_type(4))) float float4v;  // 4 f32 acc

// round-nearest-even f32 -> bf16 bits
__device__ __forceinline__ unsigned short f2bf(float f) {
    union { float f; unsigned int u; } v; v.f = f;
    unsigned int r = v.u + 0x7FFF + ((v.u >> 16) & 1);
    return (unsigned short)(r >> 16);
}

// ---------------------------------------------------------------------------
// Kernel 0 (setup): blocks 0-15 swizzle W into bf16 MFMA B-fragment-major
// order; blocks 16-28 zero the 3125 bucket cursors (64-B strided).
// ---------------------------------------------------------------------------
__global__ __launch_bounds__(256) void setup_kernel(const float* __restrict__ W,
                                                    unsigned short* __restrict__ Wf,
                                                    int* __restrict__ cursor) {
    if (blockIdx.x < 16) {
        const int f = blockIdx.x * 256 + threadIdx.x;      // < 4096
        const int lane = f & 63;
        const int qc = f >> 6;
        const int q = qc >> 3, ct = qc & 7;
        const int n = ct * 16 + (lane & 15);
        const int k0 = q * 32 + (lane >> 4) * 8;
        unsigned int o[4];
#pragma unroll
        for (int jj = 0; jj < 4; ++jj) {
            const unsigned short lo = f2bf(W[(k0 + 2 * jj) * OUT_DIM + n]);
            const unsigned short hi = f2bf(W[(k0 + 2 * jj + 1) * OUT_DIM + n]);
            o[jj] = (unsigned)lo | ((unsigned)hi << 16);
        }
        ((uint4*)Wf)[f] = make_uint4(o[0], o[1], o[2], o[3]);
    } else {
        const int i = (blockIdx.x - 16) * 256 + threadIdx.x;
        if (i < NB) {
            int4* cc = (int4*)(cursor + (i << 4));          // zero one 64-B line
            const int4 z = make_int4(0, 0, 0, 0);
            cc[0] = z; cc[1] = z; cc[2] = z; cc[3] = z;
        }
    }
}

// ---------------------------------------------------------------------------
// Kernel 1 (fused): R4-proven structure (114 us). Partition + gemm,
// interleaved 1:1 in dispatch order (blocks 0..999: even=partition, odd=gemm;
// 1000..1281: gemm). Partition: single-pass rank-from-atomic,
// register-carried (pk, src, val). ONE change vs R4: cursor words are
// 64-B strided (one cacheline per bucket) to test whether the 1.35M
// cross-XCD cursor atomics serialize at line granularity.
// ---------------------------------------------------------------------------
__global__ __launch_bounds__(512, 4) void fused_kernel(const float* __restrict__ X,
                                                       const unsigned short* __restrict__ Wf,
                                                       unsigned short* __restrict__ hb,
                                                       const int* __restrict__ src,
                                                       const int* __restrict__ dst,
                                                       const float* __restrict__ vals,
                                                       int* __restrict__ cursor,
                                                       int2* __restrict__ pairs) {
    __shared__ int smem[8192];                         // 32 KB union
    const int tid = threadIdx.x;
    const int bx = blockIdx.x;
    const bool is_part = (bx < 1000) && ((bx & 1) == 0);

    if (is_part) {
        // ================= partition branch =================
        int* lhist = smem;                             // NB ints
        int* lbase = smem + NB;                        // NB ints (25,000 B total)
        const int pid = bx >> 1;                       // 0..499
        const int base = pid * PTILE;

        for (int i = tid; i < NB; i += 512) lhist[i] = 0;
        __syncthreads();

        // single pass: histogram + rank; prefetch src/vals into registers
        // pk = b(12b)<<18 | r(13b)<<5 | d&31 ; -1 = inactive lane
        int   pk[13];
        int   sv[13];
        float vv[13];
#pragma unroll
        for (int k = 0; k < 13; ++k) {                 // 13*512 >= 6400
            const int e = base + tid + k * 512;
            pk[k] = -1;
            if (tid + k * 512 < PTILE) {
                const int d = dst[e];
                const int b = d >> 5;
                const int r = atomicAdd(&lhist[b], 1); // rank AND count
                pk[k] = (b << 18) | (r << 5) | (d & 31);
                sv[k] = src[e];
                vv[k] = vals[e];
            }
        }
        __syncthreads();

        // per-block bucket bases via global cursor (64-B strided words)
        for (int i = tid; i < NB; i += 512) {
            const int c = lhist[i];
            if (c) lbase[i] = atomicAdd(&cursor[i << 4], c);
        }
        __syncthreads();

        // scatter phase: pure stores, no re-reads, no atomics
#pragma unroll
        for (int k = 0; k < 13; ++k) {
            if (pk[k] >= 0) {
                const int b = pk[k] >> 18;
                const int r = (pk[k] >> 5) & 0x1FFF;
                const int pos = lbase[b] + r;
                if (pos < CAP)                          // overflow guard
                    pairs[(long)b * CAP + pos] =
                        make_int2(sv[k] | ((pk[k] & 31) << 20), __float_as_int(vv[k]));
            }
        }
    } else {
        // ================= gemm branch =================
        const int gid = (bx < 1000) ? (bx >> 1) : (bx - 500);   // 0..781
        const int wid = tid >> 6;                      // 8 waves x 16 rows
        const int lane = tid & 63;
        const int m = lane & 15;
        const int quad = lane >> 4;
        const int row0 = gid * 128 + wid * 16;

        // load all 8 A fragments (A[m=lane&15][k=quad*8+j], verified layout)
        const int rl = min(row0 + m, N_NODES - 1);     // clamp tail reads
        const float* xr = X + (long)rl * IN_DIM + quad * 8;
        short8 afrag[8];
#pragma unroll
        for (int q = 0; q < 8; ++q) {
            const float4 xa = *(const float4*)(xr + q * 32);
            const float4 xb = *(const float4*)(xr + q * 32 + 4);
            short8 f;
            f[0] = (short)f2bf(xa.x); f[1] = (short)f2bf(xa.y);
            f[2] = (short)f2bf(xa.z); f[3] = (short)f2bf(xa.w);
            f[4] = (short)f2bf(xb.x); f[5] = (short)f2bf(xb.y);
            f[6] = (short)f2bf(xb.z); f[7] = (short)f2bf(xb.w);
            afrag[q] = f;
        }

        // per-wave private 4 KB store stage (in-order DS: no barrier needed)
        unsigned short* stage = (unsigned short*)smem + wid * 2048;
        const short8* wfrag = (const short8*)Wf;
#pragma unroll 1
        for (int ct = 0; ct < 8; ++ct) {
            float4v acc = {0.f, 0.f, 0.f, 0.f};
#pragma unroll
            for (int q = 0; q < 8; ++q) {
                const short8 bfr = wfrag[(q * 8 + ct) * 64 + lane];
                acc = __builtin_amdgcn_mfma_f32_16x16x32_bf16(afrag[q], bfr, acc, 0, 0, 0);
            }
            // C/D: col=lane&15, row=quad*4+reg (m89-verified)
#pragma unroll
            for (int r = 0; r < 4; ++r)
                stage[(quad * 4 + r) * 128 + ct * 16 + m] = f2bf(acc[r]);
        }

        // coalesced writeback: 4 x (ds_read_b128 + dwordx4), 1 KB contiguous
#pragma unroll
        for (int j = 0; j < 4; ++j) {
            const uint4 vdata = *(const uint4*)(stage + j * 512 + lane * 8);
            const int row_r = row0 + j * 4 + quad;
            if (row_r < N_NODES)
                *(uint4*)(hb + (long)row_r * OUT_DIM + m * 8) = vdata;
        }
    }
}

// ---------------------------------------------------------------------------
// Kernel 2: CONVOY gather (R6 bug FIXED). Counting-sort each bucket's edges
// by src-range (src>>12: 25 live ~1 MB hb cells), sweep ascending so ~1280
// co-resident blocks share the same hb window in L2. Accumulate into a
// 16-KB LDS f32 out-tile via ds_add_f32. R6 BUG: the phase-2 edge loop was
// executed identically by all 4 waves -> 4x duplicate accumulation
// (absmax 50). FIX: wave-strided batches (j = wid*16, step 64) — each
// 16-edge batch processed by exactly one wave, union covers [0,cnt) once.
// ---------------------------------------------------------------------------
__global__ __launch_bounds__(256) void gather_kernel(const int* __restrict__ cursor,
                                                     const int2* __restrict__ pairs,
                                                     const unsigned short* __restrict__ hb,
                                                     const float* __restrict__ bias,
                                                     float* __restrict__ out) {
    __shared__ float acc[32][128];                     // 16,384 B f32 out-tile
    __shared__ int2 lp[CAP];                           // 10,176 B sorted pairs
    __shared__ int scnt[32];
    __shared__ int sbase[32];
    const int blk = blockIdx.x;
    const int tid = threadIdx.x;
    const int wid = tid >> 6;
    const int lane = tid & 63;

    const long beg = (long)blk * CAP;
    const int cnt = min(cursor[blk << 4], CAP);

    // zero acc tile (1024 float4) + cell counters
    {
        float4* a4 = (float4*)&acc[0][0];
        const float4 z = make_float4(0.f, 0.f, 0.f, 0.f);
#pragma unroll
        for (int k = 0; k < 4; ++k) a4[tid + k * 256] = z;
    }
    if (tid < 32) scnt[tid] = 0;
    __syncthreads();

    // phase 1a: rank by src-range s = (src>>12)&31 (cells 0..24 live)
    int2 sp[5];
    int  sr[5];
#pragma unroll
    for (int k = 0; k < 5; ++k) {                      // 5*256 = 1280 >= CAP
        const int i = tid + k * 256;
        sr[k] = -1;
        if (i < cnt) {
            const int2 p = pairs[beg + i];
            const int s = (p.x >> 12) & 31;            // src bits 12..16
            const int rk = atomicAdd(&scnt[s], 1);     // native LDS int atomic
            sp[k] = p;
            sr[k] = (s << 13) | rk;
        }
    }
    __syncthreads();

    // phase 1b: exclusive scan of 32 cell counts (wave 0, shfl scan)
    if (wid == 0) {
        const int v = (lane < 32) ? scnt[lane] : 0;
        int incl = v;
#pragma unroll
        for (int off = 1; off < 32; off <<= 1) {
            const int t = __shfl_up(incl, off);
            if (lane >= off) incl += t;
        }
        if (lane < 32) sbase[lane] = incl - v;
    }
    __syncthreads();

    // phase 1c: scatter into src-ascending LDS array
#pragma unroll
    for (int k = 0; k < 5; ++k) {
        if (sr[k] >= 0)
            lp[sbase[sr[k] >> 13] + (sr[k] & 0x1FFF)] = sp[k];
    }
    __syncthreads();

    // phase 2: src-ascending sweep, half-wave pairing, ds_add_f32 accumulate.
    // WAVE-STRIDED batches: wave w handles batches w, w+4, w+8, ... (16 edges
    // each) so every edge is accumulated exactly once.
    const int half = lane >> 5;                        // 0: even edges, 1: odd
    const int l5 = lane & 31;
    const int c4 = l5 * 4;                             // cols c4..c4+3

    for (int j = wid * 16; j < cnt; j += 64) {         // 16 edges per wave-batch
        int2 p[8];
#pragma unroll
        for (int t = 0; t < 8; ++t) {
            const int idx = j + 2 * t + half;
            int2 q = make_int2(0, 0);                  // inactive: src 0, val 0
            if (idx < cnt) q = lp[idx];
            p[t] = q;
        }
        uint2 u[8];
#pragma unroll
        for (int t = 0; t < 8; ++t)
            u[t] = *(const uint2*)(hb + (long)(p[t].x & 0xFFFFF) * OUT_DIM + c4);
#pragma unroll
        for (int t = 0; t < 8; ++t) {
            const float v = __int_as_float(p[t].y);
            const int d = (p[t].x >> 20) & 31;
            atomicAdd(&acc[d][c4],     v * __uint_as_float(u[t].x << 16));
            atomicAdd(&acc[d][c4 + 1], v * __uint_as_float(u[t].x & 0xFFFF0000u));
            atomicAdd(&acc[d][c4 + 2], v * __uint_as_float(u[t].y << 16));
            atomicAdd(&acc[d][c4 + 3], v * __uint_as_float(u[t].y & 0xFFFF0000u));
        }
    }
    __syncthreads();

    // phase 3: out-tile + bias, 16 KB contiguous coalesced writeback
    const int row = tid >> 3;                          // 0..31
    const int c0 = (tid & 7) * 16;                     // 0,16,..,112
    const long obase = (long)(blk * 32 + row) * OUT_DIM + c0;
#pragma unroll
    for (int jj = 0; jj < 4; ++jj) {
        float4 a = *(float4*)&acc[row][c0 + jj * 4];
        const float4 bv = *(const float4*)(bias + c0 + jj * 4);
        a.x += bv.x; a.y += bv.y; a.z += bv.z; a.w += bv.w;
        *(float4*)(out + obase + jj * 4) = a;
    }
}

// ---------------------------------------------------------------------------
extern "C" void kernel_launch(void* const* d_in, const int* in_sizes, int n_in,
                              void* d_out, int out_size, void* d_ws, size_t ws_size,
                              hipStream_t stream) {
    const float* X     = (const float*)d_in[0];
    const int*   esrc  = (const int*)d_in[1];
    const int*   edst  = (const int*)d_in[2];
    const float* evals = (const float*)d_in[3];
    const float* W     = (const float*)d_in[4];
    const float* b     = (const float*)d_in[5];
    float* out = (float*)d_out;

    // workspace layout (bytes) — total 57,665,536 (< 57,682,032 proven budget)
    char* ws = (char*)d_ws;
    unsigned short* hb = (unsigned short*)(ws);                  // 25,600,000
    int2* pairs        = (int2*)(ws + 25600000);                 // 31,800,000 (3125*1272*8)
    int*  cursor       = (int*) (ws + 57400000);                 //    200,000 (3125 x 64 B)
    unsigned short* Wf = (unsigned short*)(ws + 57600000);       //     65,536 (16B aligned)

    setup_kernel<<<dim3(29), dim3(256), 0, stream>>>(W, Wf, cursor);
    fused_kernel<<<dim3(PBLK + GBLK), dim3(512), 0, stream>>>(X, Wf, hb,
                                                              esrc, edst, evals,
                                                              cursor, pairs);
    gather_kernel<<<dim3(NB), dim3(256), 0, stream>>>(cursor, pairs, hb, b, out);
}

// Round 8
// 383.050 us; speedup vs baseline: 6.4502x; 6.4502x over previous
//
#include <hip/hip_runtime.h>

#define N_NODES 100000
#define IN_DIM 256
#define OUT_DIM 128
#define N_EDGES 3200000

#define NB 3125            // 100000 / 32 EXACT buckets of 32 dst nodes (no tail)
#define CAP 1272           // bucket capacity; mean 1024, sigma 32 -> +7.75 sigma
#define PTILE 6400         // edges per partition block (R4-proven)
#define PBLK 500           // 500 * 6400 = 3.2M exactly
#define GBLK 782           // ceil(100000 / 128) gemm blocks (8 waves x 16 rows)

typedef __attribute__((ext_vector_type(8))) short short8;   // 8 bf16 (4 VGPRs)
typedef __attribute__((ext_vector_type(4))) float float4v;  // 4 f32 acc

// round-nearest-even f32 -> bf16 bits
__device__ __forceinline__ unsigned short f2bf(float f) {
    union { float f; unsigned int u; } v; v.f = f;
    unsigned int r = v.u + 0x7FFF + ((v.u >> 16) & 1);
    return (unsigned short)(r >> 16);
}

// ---------------------------------------------------------------------------
// Kernel 0 (setup): blocks 0-15 swizzle W into bf16 MFMA B-fragment-major
// order; blocks 16-28 zero the 3125 bucket cursors (64-B strided).
// ---------------------------------------------------------------------------
__global__ __launch_bounds__(256) void setup_kernel(const float* __restrict__ W,
                                                    unsigned short* __restrict__ Wf,
                                                    int* __restrict__ cursor) {
    if (blockIdx.x < 16) {
        const int f = blockIdx.x * 256 + threadIdx.x;      // < 4096
        const int lane = f & 63;
        const int qc = f >> 6;
        const int q = qc >> 3, ct = qc & 7;
        const int n = ct * 16 + (lane & 15);
        const int k0 = q * 32 + (lane >> 4) * 8;
        unsigned int o[4];
#pragma unroll
        for (int jj = 0; jj < 4; ++jj) {
            const unsigned short lo = f2bf(W[(k0 + 2 * jj) * OUT_DIM + n]);
            const unsigned short hi = f2bf(W[(k0 + 2 * jj + 1) * OUT_DIM + n]);
            o[jj] = (unsigned)lo | ((unsigned)hi << 16);
        }
        ((uint4*)Wf)[f] = make_uint4(o[0], o[1], o[2], o[3]);
    } else {
        const int i = (blockIdx.x - 16) * 256 + threadIdx.x;
        if (i < NB) {
            int4* cc = (int4*)(cursor + (i << 4));          // zero one 64-B line
            const int4 z = make_int4(0, 0, 0, 0);
            cc[0] = z; cc[1] = z; cc[2] = z; cc[3] = z;
        }
    }
}

// ---------------------------------------------------------------------------
// Kernel 1 (fused): R4-proven structure (114 us). Partition + gemm,
// interleaved 1:1 in dispatch order (blocks 0..999: even=partition, odd=gemm;
// 1000..1281: gemm). Partition: single-pass rank-from-atomic,
// register-carried (pk, src, val). Cursor words 64-B strided (one cacheline
// per bucket) — R7 validated correctness; this round measures its effect.
// ---------------------------------------------------------------------------
__global__ __launch_bounds__(512, 4) void fused_kernel(const float* __restrict__ X,
                                                       const unsigned short* __restrict__ Wf,
                                                       unsigned short* __restrict__ hb,
                                                       const int* __restrict__ src,
                                                       const int* __restrict__ dst,
                                                       const float* __restrict__ vals,
                                                       int* __restrict__ cursor,
                                                       int2* __restrict__ pairs) {
    __shared__ int smem[8192];                         // 32 KB union
    const int tid = threadIdx.x;
    const int bx = blockIdx.x;
    const bool is_part = (bx < 1000) && ((bx & 1) == 0);

    if (is_part) {
        // ================= partition branch =================
        int* lhist = smem;                             // NB ints
        int* lbase = smem + NB;                        // NB ints (25,000 B total)
        const int pid = bx >> 1;                       // 0..499
        const int base = pid * PTILE;

        for (int i = tid; i < NB; i += 512) lhist[i] = 0;
        __syncthreads();

        // single pass: histogram + rank; prefetch src/vals into registers
        // pk = b(12b)<<18 | r(13b)<<5 | d&31 ; -1 = inactive lane
        int   pk[13];
        int   sv[13];
        float vv[13];
#pragma unroll
        for (int k = 0; k < 13; ++k) {                 // 13*512 >= 6400
            const int e = base + tid + k * 512;
            pk[k] = -1;
            if (tid + k * 512 < PTILE) {
                const int d = dst[e];
                const int b = d >> 5;
                const int r = atomicAdd(&lhist[b], 1); // rank AND count
                pk[k] = (b << 18) | (r << 5) | (d & 31);
                sv[k] = src[e];
                vv[k] = vals[e];
            }
        }
        __syncthreads();

        // per-block bucket bases via global cursor (64-B strided words)
        for (int i = tid; i < NB; i += 512) {
            const int c = lhist[i];
            if (c) lbase[i] = atomicAdd(&cursor[i << 4], c);
        }
        __syncthreads();

        // scatter phase: pure stores, no re-reads, no atomics
#pragma unroll
        for (int k = 0; k < 13; ++k) {
            if (pk[k] >= 0) {
                const int b = pk[k] >> 18;
                const int r = (pk[k] >> 5) & 0x1FFF;
                const int pos = lbase[b] + r;
                if (pos < CAP)                          // overflow guard
                    pairs[(long)b * CAP + pos] =
                        make_int2(sv[k] | ((pk[k] & 31) << 20), __float_as_int(vv[k]));
            }
        }
    } else {
        // ================= gemm branch =================
        const int gid = (bx < 1000) ? (bx >> 1) : (bx - 500);   // 0..781
        const int wid = tid >> 6;                      // 8 waves x 16 rows
        const int lane = tid & 63;
        const int m = lane & 15;
        const int quad = lane >> 4;
        const int row0 = gid * 128 + wid * 16;

        // load all 8 A fragments (A[m=lane&15][k=quad*8+j], verified layout)
        const int rl = min(row0 + m, N_NODES - 1);     // clamp tail reads
        const float* xr = X + (long)rl * IN_DIM + quad * 8;
        short8 afrag[8];
#pragma unroll
        for (int q = 0; q < 8; ++q) {
            const float4 xa = *(const float4*)(xr + q * 32);
            const float4 xb = *(const float4*)(xr + q * 32 + 4);
            short8 f;
            f[0] = (short)f2bf(xa.x); f[1] = (short)f2bf(xa.y);
            f[2] = (short)f2bf(xa.z); f[3] = (short)f2bf(xa.w);
            f[4] = (short)f2bf(xb.x); f[5] = (short)f2bf(xb.y);
            f[6] = (short)f2bf(xb.z); f[7] = (short)f2bf(xb.w);
            afrag[q] = f;
        }

        // per-wave private 4 KB store stage (in-order DS: no barrier needed)
        unsigned short* stage = (unsigned short*)smem + wid * 2048;
        const short8* wfrag = (const short8*)Wf;
#pragma unroll 1
        for (int ct = 0; ct < 8; ++ct) {
            float4v acc = {0.f, 0.f, 0.f, 0.f};
#pragma unroll
            for (int q = 0; q < 8; ++q) {
                const short8 bfr = wfrag[(q * 8 + ct) * 64 + lane];
                acc = __builtin_amdgcn_mfma_f32_16x16x32_bf16(afrag[q], bfr, acc, 0, 0, 0);
            }
            // C/D: col=lane&15, row=quad*4+reg (m89-verified)
#pragma unroll
            for (int r = 0; r < 4; ++r)
                stage[(quad * 4 + r) * 128 + ct * 16 + m] = f2bf(acc[r]);
        }

        // coalesced writeback: 4 x (ds_read_b128 + dwordx4), 1 KB contiguous
#pragma unroll
        for (int j = 0; j < 4; ++j) {
            const uint4 vdata = *(const uint4*)(stage + j * 512 + lane * 8);
            const int row_r = row0 + j * 4 + quad;
            if (row_r < N_NODES)
                *(uint4*)(hb + (long)row_r * OUT_DIM + m * 8) = vdata;
        }
    }
}

// ---------------------------------------------------------------------------
// Kernel 2: bucket gather-reduce — FULL REVERT to the R4-proven version
// (114 us): counting-sort by dst-row into LDS, per-row REGISTER accumulation
// (the only accumulate that costs 0 extra ops/edge), half-wave edge pairing.
// R7 lesson recorded: LDS f32 atomics at 409M scalar adds = 20x slowdown;
// convoy src-ordering left FETCH unchanged (co-resident blocks don't stay
// phase-locked). Only deltas vs R4: cursor[blk<<4] (strided) and CAP 1272.
// ---------------------------------------------------------------------------
__global__ __launch_bounds__(256) void gather_kernel(const int* __restrict__ cursor,
                                                     const int2* __restrict__ pairs,
                                                     const unsigned short* __restrict__ hb,
                                                     const float* __restrict__ bias,
                                                     float* __restrict__ out) {
    __shared__ int2 lp[CAP];                           // 10,176 B sorted pairs
    __shared__ int rcnt[32];
    __shared__ int rbase[32];
    const int blk = blockIdx.x;
    const int tid = threadIdx.x;
    const int wid = tid >> 6;
    const int lane = tid & 63;

    const long beg = (long)blk * CAP;
    const int cnt = min(cursor[blk << 4], CAP);

    if (tid < 32) rcnt[tid] = 0;
    __syncthreads();

    // phase 1a: rank by dst row (5*256 = 1280 >= CAP)
    int2 sp[5];
    int  sr[5];
#pragma unroll
    for (int k = 0; k < 5; ++k) {
        const int i = tid + k * 256;
        sr[k] = -1;
        if (i < cnt) {
            const int2 p = pairs[beg + i];
            const int r = (p.x >> 20) & 31;
            const int rk = atomicAdd(&rcnt[r], 1);     // native LDS int atomic
            sp[k] = p;
            sr[k] = (r << 13) | rk;
        }
    }
    __syncthreads();

    // phase 1b: exclusive scan of 32 row counts (wave 0, shfl scan)
    if (wid == 0) {
        const int v = (lane < 32) ? rcnt[lane] : 0;
        int incl = v;
#pragma unroll
        for (int off = 1; off < 32; off <<= 1) {
            const int t = __shfl_up(incl, off);
            if (lane >= off) incl += t;
        }
        if (lane < 32) rbase[lane] = incl - v;
    }
    __syncthreads();

    // phase 1c: scatter into row-sorted LDS array
#pragma unroll
    for (int k = 0; k < 5; ++k) {
        if (sr[k] >= 0)
            lp[rbase[sr[k] >> 13] + (sr[k] & 0x1FFF)] = sp[k];
    }
    __syncthreads();

    // phase 2: per-row register accumulation, half-wave edge pairing.
    const int half = lane >> 5;                        // 0: even edges, 1: odd
    const int l5 = lane & 31;
    const int c4 = l5 * 4;                             // cols c4..c4+3
    const float4 bb = *(const float4*)(bias + c4);

#pragma unroll 1
    for (int rr = 0; rr < 8; ++rr) {                   // each wave owns 8 rows
        const int r = wid * 8 + rr;
        const int node = blk * 32 + r;                 // always < 100000
        const int rb = rbase[r];
        const int re = rb + rcnt[r];

        float4 acc0 = {0.f, 0.f, 0.f, 0.f};
        float4 acc1 = {0.f, 0.f, 0.f, 0.f};

        for (int j = rb; j < re; j += 16) {            // 16 edges per batch
            int2 p[8];
#pragma unroll
            for (int t = 0; t < 8; ++t) {
                const int idx = j + 2 * t + half;
                int2 q = make_int2(0, 0);              // inactive: src 0, val 0
                if (idx < re) q = lp[idx];             // broadcast-addr ds_read
                p[t] = q;
            }
            uint2 u[8];
#pragma unroll
            for (int t = 0; t < 8; ++t)
                u[t] = *(const uint2*)(hb + (long)(p[t].x & 0xFFFFF) * OUT_DIM + c4);
#pragma unroll
            for (int t = 0; t < 8; ++t) {
                const float v = __int_as_float(p[t].y);
                const float f0 = __uint_as_float(u[t].x << 16);
                const float f1 = __uint_as_float(u[t].x & 0xFFFF0000u);
                const float f2 = __uint_as_float(u[t].y << 16);
                const float f3 = __uint_as_float(u[t].y & 0xFFFF0000u);
                if ((t & 1) == 0) {
                    acc0.x += v * f0; acc0.y += v * f1;
                    acc0.z += v * f2; acc0.w += v * f3;
                } else {
                    acc1.x += v * f0; acc1.y += v * f1;
                    acc1.z += v * f2; acc1.w += v * f3;
                }
            }
        }

        // cross-half reduce (even-edge half + odd-edge half), then store
        float4 s;
        s.x = acc0.x + acc1.x; s.y = acc0.y + acc1.y;
        s.z = acc0.z + acc1.z; s.w = acc0.w + acc1.w;
        s.x += __shfl_xor(s.x, 32);
        s.y += __shfl_xor(s.y, 32);
        s.z += __shfl_xor(s.z, 32);
        s.w += __shfl_xor(s.w, 32);
        if (half == 0) {
            float4 o = make_float4(bb.x + s.x, bb.y + s.y, bb.z + s.z, bb.w + s.w);
            *(float4*)(out + (long)node * OUT_DIM + c4) = o;   // 512B/half-wave
        }
    }
}

// ---------------------------------------------------------------------------
extern "C" void kernel_launch(void* const* d_in, const int* in_sizes, int n_in,
                              void* d_out, int out_size, void* d_ws, size_t ws_size,
                              hipStream_t stream) {
    const float* X     = (const float*)d_in[0];
    const int*   esrc  = (const int*)d_in[1];
    const int*   edst  = (const int*)d_in[2];
    const float* evals = (const float*)d_in[3];
    const float* W     = (const float*)d_in[4];
    const float* b     = (const float*)d_in[5];
    float* out = (float*)d_out;

    // workspace layout (bytes) — total 57,665,536 (< 57,682,032 proven budget)
    char* ws = (char*)d_ws;
    unsigned short* hb = (unsigned short*)(ws);                  // 25,600,000
    int2* pairs        = (int2*)(ws + 25600000);                 // 31,800,000 (3125*1272*8)
    int*  cursor       = (int*) (ws + 57400000);                 //    200,000 (3125 x 64 B)
    unsigned short* Wf = (unsigned short*)(ws + 57600000);       //     65,536 (16B aligned)

    setup_kernel<<<dim3(29), dim3(256), 0, stream>>>(W, Wf, cursor);
    fused_kernel<<<dim3(PBLK + GBLK), dim3(512), 0, stream>>>(X, Wf, hb,
                                                              esrc, edst, evals,
                                                              cursor, pairs);
    gather_kernel<<<dim3(NB), dim3(256), 0, stream>>>(cursor, pairs, hb, b, out);
}

// Round 9
// 365.811 us; speedup vs baseline: 6.7541x; 1.0471x over previous
//
#include <hip/hip_runtime.h>

#define N_NODES 100000
#define IN_DIM 256
#define OUT_DIM 128
#define N_EDGES 3200000

#define NB 3125            // 100000 / 32 EXACT buckets of 32 dst nodes (no tail)
#define CAP 1280           // bucket capacity; mean 1024, sigma 32 -> 8 sigma slack
#define PTILE 6400         // edges per partition block
#define PBLK 500           // 500 * 6400 = 3.2M exactly
#define GBLK 782           // ceil(100000 / 128) gemm blocks (8 waves x 16 rows)

typedef __attribute__((ext_vector_type(8))) short short8;   // 8 bf16 (4 VGPRs)
typedef __attribute__((ext_vector_type(4))) float float4v;  // 4 f32 acc

// round-nearest-even f32 -> bf16 bits
__device__ __forceinline__ unsigned short f2bf(float f) {
    union { float f; unsigned int u; } v; v.f = f;
    unsigned int r = v.u + 0x7FFF + ((v.u >> 16) & 1);
    return (unsigned short)(r >> 16);
}

// ---------------------------------------------------------------------------
// Kernel 0 (setup): blocks 0-15 swizzle W into bf16 MFMA B-fragment-major
// order; blocks 16-28 zero the 3125 bucket cursors (PACKED — 16 cursors per
// 64-B line. R8 measured: strided 1-cursor-per-line is 22 us WORSE on fused;
// packed same-line atomics get combined at the TCC atomic unit).
// ---------------------------------------------------------------------------
__global__ __launch_bounds__(256) void setup_kernel(const float* __restrict__ W,
                                                    unsigned short* __restrict__ Wf,
                                                    int* __restrict__ cursor) {
    if (blockIdx.x < 16) {
        const int f = blockIdx.x * 256 + threadIdx.x;      // < 4096
        const int lane = f & 63;
        const int qc = f >> 6;
        const int q = qc >> 3, ct = qc & 7;
        const int n = ct * 16 + (lane & 15);
        const int k0 = q * 32 + (lane >> 4) * 8;
        unsigned int o[4];
#pragma unroll
        for (int jj = 0; jj < 4; ++jj) {
            const unsigned short lo = f2bf(W[(k0 + 2 * jj) * OUT_DIM + n]);
            const unsigned short hi = f2bf(W[(k0 + 2 * jj + 1) * OUT_DIM + n]);
            o[jj] = (unsigned)lo | ((unsigned)hi << 16);
        }
        ((uint4*)Wf)[f] = make_uint4(o[0], o[1], o[2], o[3]);
    } else {
        const int i = (blockIdx.x - 16) * 256 + threadIdx.x;
        if (i < NB) cursor[i] = 0;
    }
}

// ---------------------------------------------------------------------------
// Kernel 1 (fused): R4-proven structure (114.5 us measured). Partition +
// gemm, interleaved 1:1 in dispatch order (blocks 0..999: even=partition,
// odd=gemm; 1000..1281: gemm) so each CU co-hosts latency-bound partition
// waves and MFMA gemm waves. Partition: single-pass rank-from-atomic,
// register-carried (pk, src, val); pk = b(12b)<<18 | r(13b)<<5 | d&31.
// Cursor atomics PACKED (R8 A/B: packed beats strided by 22 us).
// ---------------------------------------------------------------------------
__global__ __launch_bounds__(512, 4) void fused_kernel(const float* __restrict__ X,
                                                       const unsigned short* __restrict__ Wf,
                                                       unsigned short* __restrict__ hb,
                                                       const int* __restrict__ src,
                                                       const int* __restrict__ dst,
                                                       const float* __restrict__ vals,
                                                       int* __restrict__ cursor,
                                                       int2* __restrict__ pairs) {
    __shared__ int smem[8192];                         // 32 KB union
    const int tid = threadIdx.x;
    const int bx = blockIdx.x;
    const bool is_part = (bx < 1000) && ((bx & 1) == 0);

    if (is_part) {
        // ================= partition branch =================
        int* lhist = smem;                             // NB ints
        int* lbase = smem + NB;                        // NB ints (25,000 B total)
        const int pid = bx >> 1;                       // 0..499
        const int base = pid * PTILE;

        for (int i = tid; i < NB; i += 512) lhist[i] = 0;
        __syncthreads();

        // single pass: histogram + rank; prefetch src/vals into registers
#pragma unroll
        for (int k = 0; k < 13; ++k) {                 // 13*512 >= 6400
            const int e = base + tid + k * 512;
            // (declared below to keep arrays in registers)
        }
        int   pk[13];
        int   sv[13];
        float vv[13];
#pragma unroll
        for (int k = 0; k < 13; ++k) {
            const int e = base + tid + k * 512;
            pk[k] = -1;
            if (tid + k * 512 < PTILE) {
                const int d = dst[e];
                const int b = d >> 5;
                const int r = atomicAdd(&lhist[b], 1); // rank AND count
                pk[k] = (b << 18) | (r << 5) | (d & 31);
                sv[k] = src[e];
                vv[k] = vals[e];
            }
        }
        __syncthreads();

        // per-block bucket bases via global cursor (packed words)
        for (int i = tid; i < NB; i += 512) {
            const int c = lhist[i];
            if (c) lbase[i] = atomicAdd(&cursor[i], c);
        }
        __syncthreads();

        // scatter phase: pure stores, no re-reads, no atomics
#pragma unroll
        for (int k = 0; k < 13; ++k) {
            if (pk[k] >= 0) {
                const int b = pk[k] >> 18;
                const int r = (pk[k] >> 5) & 0x1FFF;
                const int pos = lbase[b] + r;
                if (pos < CAP)                          // 8-sigma overflow guard
                    pairs[(long)b * CAP + pos] =
                        make_int2(sv[k] | ((pk[k] & 31) << 20), __float_as_int(vv[k]));
            }
        }
    } else {
        // ================= gemm branch =================
        const int gid = (bx < 1000) ? (bx >> 1) : (bx - 500);   // 0..781
        const int wid = tid >> 6;                      // 8 waves x 16 rows
        const int lane = tid & 63;
        const int m = lane & 15;
        const int quad = lane >> 4;
        const int row0 = gid * 128 + wid * 16;

        // load all 8 A fragments (A[m=lane&15][k=quad*8+j], verified layout)
        const int rl = min(row0 + m, N_NODES - 1);     // clamp tail reads
        const float* xr = X + (long)rl * IN_DIM + quad * 8;
        short8 afrag[8];
#pragma unroll
        for (int q = 0; q < 8; ++q) {
            const float4 xa = *(const float4*)(xr + q * 32);
            const float4 xb = *(const float4*)(xr + q * 32 + 4);
            short8 f;
            f[0] = (short)f2bf(xa.x); f[1] = (short)f2bf(xa.y);
            f[2] = (short)f2bf(xa.z); f[3] = (short)f2bf(xa.w);
            f[4] = (short)f2bf(xb.x); f[5] = (short)f2bf(xb.y);
            f[6] = (short)f2bf(xb.z); f[7] = (short)f2bf(xb.w);
            afrag[q] = f;
        }

        // per-wave private 4 KB store stage (in-order DS: no barrier needed)
        unsigned short* stage = (unsigned short*)smem + wid * 2048;
        const short8* wfrag = (const short8*)Wf;
#pragma unroll 1
        for (int ct = 0; ct < 8; ++ct) {
            float4v acc = {0.f, 0.f, 0.f, 0.f};
#pragma unroll
            for (int q = 0; q < 8; ++q) {
                const short8 bfr = wfrag[(q * 8 + ct) * 64 + lane];
                acc = __builtin_amdgcn_mfma_f32_16x16x32_bf16(afrag[q], bfr, acc, 0, 0, 0);
            }
            // C/D: col=lane&15, row=quad*4+reg (m89-verified)
#pragma unroll
            for (int r = 0; r < 4; ++r)
                stage[(quad * 4 + r) * 128 + ct * 16 + m] = f2bf(acc[r]);
        }

        // coalesced writeback: 4 x (ds_read_b128 + dwordx4), 1 KB contiguous
#pragma unroll
        for (int j = 0; j < 4; ++j) {
            const uint4 vdata = *(const uint4*)(stage + j * 512 + lane * 8);
            const int row_r = row0 + j * 4 + quad;
            if (row_r < N_NODES)
                *(uint4*)(hb + (long)row_r * OUT_DIM + m * 8) = vdata;
        }
    }
}

// ---------------------------------------------------------------------------
// Kernel 2: bucket gather-reduce — R4-proven version (114.2 us measured):
// counting-sort by dst-row into LDS, per-row REGISTER accumulation (0 extra
// ops/edge), half-wave edge pairing (2 edges per wave-instruction stream,
// uint2 gathers). Pinned at the ~3.1 TB/s XCD<->L3 fabric: FETCH 353 MB
// invariant across three structures (R1/R4/R7) — structural floor 205 MB
// (hb once per XCD) unreachable with uniform-random src.
// ---------------------------------------------------------------------------
__global__ __launch_bounds__(256) void gather_kernel(const int* __restrict__ cursor,
                                                     const int2* __restrict__ pairs,
                                                     const unsigned short* __restrict__ hb,
                                                     const float* __restrict__ bias,
                                                     float* __restrict__ out) {
    __shared__ int2 lp[CAP];                           // 10,240 B sorted pairs
    __shared__ int rcnt[32];
    __shared__ int rbase[32];
    const int blk = blockIdx.x;
    const int tid = threadIdx.x;
    const int wid = tid >> 6;
    const int lane = tid & 63;

    const long beg = (long)blk * CAP;
    const int cnt = min(cursor[blk], CAP);

    if (tid < 32) rcnt[tid] = 0;
    __syncthreads();

    // phase 1a: rank by dst row (CAP = 5 * 256 exactly)
    int2 sp[5];
    int  sr[5];
#pragma unroll
    for (int k = 0; k < 5; ++k) {
        const int i = tid + k * 256;
        sr[k] = -1;
        if (i < cnt) {
            const int2 p = pairs[beg + i];
            const int r = (p.x >> 20) & 31;
            const int rk = atomicAdd(&rcnt[r], 1);     // native LDS int atomic
            sp[k] = p;
            sr[k] = (r << 13) | rk;
        }
    }
    __syncthreads();

    // phase 1b: exclusive scan of 32 row counts (wave 0, shfl scan)
    if (wid == 0) {
        const int v = (lane < 32) ? rcnt[lane] : 0;
        int incl = v;
#pragma unroll
        for (int off = 1; off < 32; off <<= 1) {
            const int t = __shfl_up(incl, off);
            if (lane >= off) incl += t;
        }
        if (lane < 32) rbase[lane] = incl - v;
    }
    __syncthreads();

    // phase 1c: scatter into row-sorted LDS array
#pragma unroll
    for (int k = 0; k < 5; ++k) {
        if (sr[k] >= 0)
            lp[rbase[sr[k] >> 13] + (sr[k] & 0x1FFF)] = sp[k];
    }
    __syncthreads();

    // phase 2: per-row register accumulation, half-wave edge pairing.
    const int half = lane >> 5;                        // 0: even edges, 1: odd
    const int l5 = lane & 31;
    const int c4 = l5 * 4;                             // cols c4..c4+3
    const float4 bb = *(const float4*)(bias + c4);

#pragma unroll 1
    for (int rr = 0; rr < 8; ++rr) {                   // each wave owns 8 rows
        const int r = wid * 8 + rr;
        const int node = blk * 32 + r;                 // always < 100000
        const int rb = rbase[r];
        const int re = rb + rcnt[r];

        float4 acc0 = {0.f, 0.f, 0.f, 0.f};
        float4 acc1 = {0.f, 0.f, 0.f, 0.f};

        for (int j = rb; j < re; j += 16) {            // 16 edges per batch
            int2 p[8];
#pragma unroll
            for (int t = 0; t < 8; ++t) {
                const int idx = j + 2 * t + half;
                int2 q = make_int2(0, 0);              // inactive: src 0, val 0
                if (idx < re) q = lp[idx];             // broadcast-addr ds_read
                p[t] = q;
            }
            uint2 u[8];
#pragma unroll
            for (int t = 0; t < 8; ++t)
                u[t] = *(const uint2*)(hb + (long)(p[t].x & 0xFFFFF) * OUT_DIM + c4);
#pragma unroll
            for (int t = 0; t < 8; ++t) {
                const float v = __int_as_float(p[t].y);
                const float f0 = __uint_as_float(u[t].x << 16);
                const float f1 = __uint_as_float(u[t].x & 0xFFFF0000u);
                const float f2 = __uint_as_float(u[t].y << 16);
                const float f3 = __uint_as_float(u[t].y & 0xFFFF0000u);
                if ((t & 1) == 0) {
                    acc0.x += v * f0; acc0.y += v * f1;
                    acc0.z += v * f2; acc0.w += v * f3;
                } else {
                    acc1.x += v * f0; acc1.y += v * f1;
                    acc1.z += v * f2; acc1.w += v * f3;
                }
            }
        }

        // cross-half reduce (even-edge half + odd-edge half), then store
        float4 s;
        s.x = acc0.x + acc1.x; s.y = acc0.y + acc1.y;
        s.z = acc0.z + acc1.z; s.w = acc0.w + acc1.w;
        s.x += __shfl_xor(s.x, 32);
        s.y += __shfl_xor(s.y, 32);
        s.z += __shfl_xor(s.z, 32);
        s.w += __shfl_xor(s.w, 32);
        if (half == 0) {
            float4 o = make_float4(bb.x + s.x, bb.y + s.y, bb.z + s.z, bb.w + s.w);
            *(float4*)(out + (long)node * OUT_DIM + c4) = o;   // 512B/half-wave
        }
    }
}

// ---------------------------------------------------------------------------
extern "C" void kernel_launch(void* const* d_in, const int* in_sizes, int n_in,
                              void* d_out, int out_size, void* d_ws, size_t ws_size,
                              hipStream_t stream) {
    const float* X     = (const float*)d_in[0];
    const int*   esrc  = (const int*)d_in[1];
    const int*   edst  = (const int*)d_in[2];
    const float* evals = (const float*)d_in[3];
    const float* W     = (const float*)d_in[4];
    const float* b     = (const float*)d_in[5];
    float* out = (float*)d_out;

    // workspace layout (bytes) — total 57,678,048 (< 57,682,032 proven budget)
    char* ws = (char*)d_ws;
    unsigned short* hb = (unsigned short*)(ws);                  // 25,600,000
    int2* pairs        = (int2*)(ws + 25600000);                 // 32,000,000 (3125*1280*8)
    int*  cursor       = (int*) (ws + 25600000 + 32000000);      //     12,500 (packed)
    unsigned short* Wf = (unsigned short*)(ws + 57612512);       //     65,536 (16B aligned)

    setup_kernel<<<dim3(29), dim3(256), 0, stream>>>(W, Wf, cursor);
    fused_kernel<<<dim3(PBLK + GBLK), dim3(512), 0, stream>>>(X, Wf, hb,
                                                              esrc, edst, evals,
                                                              cursor, pairs);
    gather_kernel<<<dim3(NB), dim3(256), 0, stream>>>(cursor, pairs, hb, b, out);
}